// Round 3
// baseline (315.512 us; speedup 1.0000x reference)
//
#include <hip/hip_runtime.h>
#include <hip/hip_bf16.h>

#define N_TOK 32768
#define DIM   192
#define HID   384
#define NEXP  8
#define BM    64

#define KT1 6     // DIM/32
#define KT2 12    // HID/32
#define JTL1 12   // half of HID in 16-col tiles
#define JTL2 6    // half of DIM in 16-col tiles
#define NB   32   // blocks per (expert, jhalf)
#define WCHUNK 73728   // bytes of packed weights per (expert, jhalf)

#define EPSV 2.220446049250313e-16f

typedef __attribute__((ext_vector_type(8))) short short8;
typedef __attribute__((ext_vector_type(4))) short short4v;
typedef __attribute__((ext_vector_type(4))) float f32x4;

static __device__ __forceinline__ short f2bf(float f) {
    union { __hip_bfloat16 h; short s; } u;
    u.h = __float2bfloat16(f);
    return u.s;
}

typedef const __attribute__((address_space(1))) void* gptr_t;
typedef __attribute__((address_space(3))) void* lptr_t;
#define GLOAD_LDS16(g, l) \
    __builtin_amdgcn_global_load_lds((gptr_t)(const void*)(g), (lptr_t)(void*)(l), 16, 0, 0)

// ---------------------------------------------------------------------------
// Gating: logits = [x,emb] @ w_gate ; top-2 ; softmax ; scatter to expert lists.
// Optionally emits x as bf16 rows (A-operand for pass 1).
// 128 threads x 256 blocks -> covers all CUs.
// ---------------------------------------------------------------------------
template<bool WXB>
__global__ __launch_bounds__(128) void gate_kernel(
    const float* __restrict__ x, const float* __restrict__ emb,
    const float* __restrict__ wg,
    int* __restrict__ counts, int* __restrict__ toks, float* __restrict__ gates,
    short* __restrict__ xb)
{
    __shared__ float wgs[2 * DIM * NEXP];   // 12 KB
    __shared__ int cnt[NEXP];
    __shared__ int base[NEXP];
    int tid = threadIdx.x;
    for (int i = tid; i < 2 * DIM * NEXP; i += 128) wgs[i] = wg[i];
    if (tid < NEXP) cnt[tid] = 0;
    __syncthreads();

    int t = blockIdx.x * 128 + tid;
    float acc[NEXP];
#pragma unroll
    for (int e = 0; e < NEXP; ++e) acc[e] = 0.f;

    const float4* xp = reinterpret_cast<const float4*>(x + (size_t)t * DIM);
    const float4* ep = reinterpret_cast<const float4*>(emb + (size_t)t * DIM);
    short* xrow = WXB ? (xb + (size_t)t * DIM) : nullptr;
#pragma unroll 2
    for (int i = 0; i < DIM / 4; ++i) {
        float4 v = xp[i];
        if (WXB) {
            short4v s; s[0] = f2bf(v.x); s[1] = f2bf(v.y); s[2] = f2bf(v.z); s[3] = f2bf(v.w);
            *reinterpret_cast<short4v*>(xrow + i * 4) = s;
        }
        const float* wr = &wgs[(i * 4) * NEXP];
#pragma unroll
        for (int e = 0; e < NEXP; ++e) acc[e] += v.x * wr[e];
#pragma unroll
        for (int e = 0; e < NEXP; ++e) acc[e] += v.y * wr[NEXP + e];
#pragma unroll
        for (int e = 0; e < NEXP; ++e) acc[e] += v.z * wr[2 * NEXP + e];
#pragma unroll
        for (int e = 0; e < NEXP; ++e) acc[e] += v.w * wr[3 * NEXP + e];
    }
#pragma unroll 2
    for (int i = 0; i < DIM / 4; ++i) {
        float4 v = ep[i];
        const float* wr = &wgs[(DIM + i * 4) * NEXP];
#pragma unroll
        for (int e = 0; e < NEXP; ++e) acc[e] += v.x * wr[e];
#pragma unroll
        for (int e = 0; e < NEXP; ++e) acc[e] += v.y * wr[NEXP + e];
#pragma unroll
        for (int e = 0; e < NEXP; ++e) acc[e] += v.z * wr[2 * NEXP + e];
#pragma unroll
        for (int e = 0; e < NEXP; ++e) acc[e] += v.w * wr[3 * NEXP + e];
    }

    int i1 = 0; float l1 = acc[0];
#pragma unroll
    for (int e = 1; e < NEXP; ++e) { if (acc[e] > l1) { l1 = acc[e]; i1 = e; } }
    int i2 = -1; float l2 = -1e30f;
#pragma unroll
    for (int e = 0; e < NEXP; ++e) { if (e != i1 && acc[e] > l2) { l2 = acc[e]; i2 = e; } }
    float g1 = 1.f / (1.f + expf(l2 - l1));
    float g2 = 1.f - g1;

    int p1 = atomicAdd(&cnt[i1], 1);
    int p2 = atomicAdd(&cnt[i2], 1);
    __syncthreads();
    if (tid < NEXP) base[tid] = atomicAdd(&counts[tid], cnt[tid]);
    __syncthreads();
    int o1 = base[i1] + p1;
    int o2 = base[i2] + p2;
    toks[i1 * N_TOK + o1]  = (t << 1);
    gates[i1 * N_TOK + o1] = g1;
    toks[i2 * N_TOK + o2]  = (t << 1) | 1;
    gates[i2 * N_TOK + o2] = g2;
}

// ---------------------------------------------------------------------------
// Pack w1/w2 -> bf16 MFMA B-fragment order, contiguous per (e, jhalf):
//   pb1[e][jh][kt(6)][jtl(12)][lane(64)][8]   (jh splits HID in halves of 192)
//   pb2[e][jh][kt(12)][jtl(6)][lane(64)][8]   (jh splits DIM in halves of 96)
// Output-centric: one thread = one 16B fragment write (coalesced).
// ---------------------------------------------------------------------------
__global__ __launch_bounds__(256) void pack_kernel(
    const float* __restrict__ w1, const float* __restrict__ w2,
    short* __restrict__ pb1, short* __restrict__ pb2)
{
    const int Q = NEXP * 2 * KT1 * JTL1 * 64;   // 73728 fragments per tensor
    int gid = blockIdx.x * 256 + threadIdx.x;
    if (gid < Q) {
        int lane = gid & 63;
        int r = gid >> 6;
        int jtl = r % JTL1; r /= JTL1;
        int kt  = r % KT1;  r /= KT1;
        int jh  = r & 1;    int e = r >> 1;
        int j  = jh * 192 + jtl * 16 + (lane & 15);
        int k0 = kt * 32 + (lane >> 4) * 8;
        const float* src = w1 + ((size_t)e * DIM + k0) * HID + j;
        short8 s;
#pragma unroll
        for (int t = 0; t < 8; ++t) s[t] = f2bf(src[t * HID]);
        *reinterpret_cast<short8*>(pb1 + (size_t)gid * 8) = s;
    } else if (gid < 2 * Q) {
        int i2 = gid - Q;
        int lane = i2 & 63;
        int r = i2 >> 6;
        int jtl = r % JTL2; r /= JTL2;
        int kt  = r % KT2;  r /= KT2;
        int jh  = r & 1;    int e = r >> 1;
        int j  = jh * 96 + jtl * 16 + (lane & 15);
        int k0 = kt * 32 + (lane >> 4) * 8;
        const float* src = w2 + ((size_t)e * HID + k0) * DIM + j;
        short8 s;
#pragma unroll
        for (int t = 0; t < 8; ++t) s[t] = f2bf(src[t * DIM]);
        *reinterpret_cast<short8*>(pb2 + (size_t)i2 * 8) = s;
    }
}

// ---------------------------------------------------------------------------
// Pass 1: H[tk][jh*192 + :192] = gelu(x[tok] @ w1[e][:, jhalf] + b1)
// Persistent weights: block = (e, jh, nb); stages 72KB once, loops tiles.
// No barriers in the main loop.
// ---------------------------------------------------------------------------
template<bool USE_XB>
__global__ __launch_bounds__(256) void h_kernel(
    const float* __restrict__ x, const short* __restrict__ xb,
    const short* __restrict__ pb1, const float* __restrict__ b1,
    const int* __restrict__ counts, const int* __restrict__ toks,
    short* __restrict__ H)
{
    int b = blockIdx.x;
    int nb = b & (NB - 1);
    int jh = (b >> 5) & 1;
    int e  = b >> 6;
    int cnt = counts[e];
    int ntiles = (cnt + BM - 1) / BM;

    __shared__ __align__(16) char wlds[WCHUNK];   // 72 KB
    int tid = threadIdx.x;
    const char* wsrc = reinterpret_cast<const char*>(pb1) + (size_t)(e * 2 + jh) * WCHUNK;
#pragma unroll
    for (int i = 0; i < 18; ++i)
        GLOAD_LDS16(wsrc + i * 4096 + tid * 16, wlds + i * 4096 + tid * 16);
    __syncthreads();

    int wave = tid >> 6, lane = tid & 63;
    int lrow = lane & 15, lgrp = lane >> 4;
    int row0 = wave * 16;
    int r0 = row0 + lgrp * 4;
    const int* tlist = toks + e * N_TOK;
    const float* b1j = b1 + e * HID + jh * 192;

    for (int t = nb; t < ntiles; t += NB) {
        int m0 = t * BM;
        int ridx = m0 + row0 + lrow;
        int tokA = (ridx < cnt) ? (tlist[ridx] >> 1) : 0;

        short8 af[KT1];
        if (USE_XB) {
            const char* xr = reinterpret_cast<const char*>(xb) + (size_t)tokA * 384 + lgrp * 16;
#pragma unroll
            for (int kt = 0; kt < KT1; ++kt)
                af[kt] = *reinterpret_cast<const short8*>(xr + kt * 64);
        } else {
            const char* xr = reinterpret_cast<const char*>(x) + (size_t)tokA * 768 + lgrp * 32;
#pragma unroll
            for (int kt = 0; kt < KT1; ++kt) {
                float4 a0 = *reinterpret_cast<const float4*>(xr + kt * 128);
                float4 a1 = *reinterpret_cast<const float4*>(xr + kt * 128 + 16);
                short8 s;
                s[0] = f2bf(a0.x); s[1] = f2bf(a0.y); s[2] = f2bf(a0.z); s[3] = f2bf(a0.w);
                s[4] = f2bf(a1.x); s[5] = f2bf(a1.y); s[6] = f2bf(a1.z); s[7] = f2bf(a1.w);
                af[kt] = s;
            }
        }

        f32x4 acc[JTL1];
#pragma unroll
        for (int j = 0; j < JTL1; ++j) acc[j] = (f32x4){0.f, 0.f, 0.f, 0.f};
#pragma unroll
        for (int kt = 0; kt < KT1; ++kt) {
#pragma unroll
            for (int jtl = 0; jtl < JTL1; ++jtl) {
                short8 bb = *reinterpret_cast<const short8*>(wlds + (kt * JTL1 + jtl) * 1024 + lane * 16);
                acc[jtl] = __builtin_amdgcn_mfma_f32_16x16x32_bf16(af[kt], bb, acc[jtl], 0, 0, 0);
            }
        }

#pragma unroll
        for (int rr = 0; rr < 4; ++rr) {
            int r = m0 + r0 + rr;
            if (r < cnt) {
                int tk = tlist[r];
                short* hrow = H + (size_t)tk * HID + jh * 192;
#pragma unroll
                for (int jtl = 0; jtl < JTL1; ++jtl) {
                    int col = jtl * 16 + lrow;
                    float h = acc[jtl][rr] + b1j[col];
                    float g = 0.5f * h * (1.f + erff(h * 0.70710678118654752f));
                    hrow[col] = f2bf(g);
                }
            }
        }
    }
}

// ---------------------------------------------------------------------------
// Pass 2: slot[tk][jh*96 + :96] = gate * exp(H[tk] @ w2[e][:, jhalf] + b2)
// ---------------------------------------------------------------------------
__global__ __launch_bounds__(256) void y_kernel(
    const short* __restrict__ H,
    const short* __restrict__ pb2, const float* __restrict__ b2,
    const int* __restrict__ counts, const int* __restrict__ toks,
    const float* __restrict__ gates,
    float* __restrict__ slot)
{
    int b = blockIdx.x;
    int nb = b & (NB - 1);
    int jh = (b >> 5) & 1;
    int e  = b >> 6;
    int cnt = counts[e];
    int ntiles = (cnt + BM - 1) / BM;

    __shared__ __align__(16) char wlds[WCHUNK];   // 72 KB
    int tid = threadIdx.x;
    const char* wsrc = reinterpret_cast<const char*>(pb2) + (size_t)(e * 2 + jh) * WCHUNK;
#pragma unroll
    for (int i = 0; i < 18; ++i)
        GLOAD_LDS16(wsrc + i * 4096 + tid * 16, wlds + i * 4096 + tid * 16);
    __syncthreads();

    int wave = tid >> 6, lane = tid & 63;
    int lrow = lane & 15, lgrp = lane >> 4;
    int row0 = wave * 16;
    int r0 = row0 + lgrp * 4;
    const int* tlist = toks + e * N_TOK;
    const float* glist = gates + e * N_TOK;
    const float* b2j = b2 + e * DIM + jh * 96;

    for (int t = nb; t < ntiles; t += NB) {
        int m0 = t * BM;
        int ridx = m0 + row0 + lrow;
        int tka = (ridx < cnt) ? tlist[ridx] : 0;

        short8 af[KT2];
        {
            const char* hr = reinterpret_cast<const char*>(H) + (size_t)tka * 768 + lgrp * 16;
#pragma unroll
            for (int kt = 0; kt < KT2; ++kt)
                af[kt] = *reinterpret_cast<const short8*>(hr + kt * 64);
        }

        f32x4 acc[JTL2];
#pragma unroll
        for (int j = 0; j < JTL2; ++j) acc[j] = (f32x4){0.f, 0.f, 0.f, 0.f};
#pragma unroll
        for (int kt = 0; kt < KT2; ++kt) {
#pragma unroll
            for (int jtl = 0; jtl < JTL2; ++jtl) {
                short8 bb = *reinterpret_cast<const short8*>(wlds + (kt * JTL2 + jtl) * 1024 + lane * 16);
                acc[jtl] = __builtin_amdgcn_mfma_f32_16x16x32_bf16(af[kt], bb, acc[jtl], 0, 0, 0);
            }
        }

#pragma unroll
        for (int rr = 0; rr < 4; ++rr) {
            int r = m0 + r0 + rr;
            if (r < cnt) {
                int tk = tlist[r];
                float g = glist[r];
                float* srow = slot + (size_t)tk * DIM + jh * 96;
#pragma unroll
                for (int jtl = 0; jtl < JTL2; ++jtl) {
                    int col = jtl * 16 + lrow;
                    float y = acc[jtl][rr] + b2j[col];
                    srow[col] = g * expf(y);
                }
            }
        }
    }
}

// ---------------------------------------------------------------------------
// out[t][:] = log(slot[2t][:] + slot[2t+1][:])   (vectorized)
// ---------------------------------------------------------------------------
__global__ __launch_bounds__(256) void combine_kernel(
    const float* __restrict__ sb, float* __restrict__ out)
{
    int i = blockIdx.x * 256 + threadIdx.x;   // over N_TOK*DIM/4
    int t = i / 48;
    int j = (i - t * 48) * 4;
    const float* r = sb + (size_t)t * (2 * DIM);
    float4 a = *reinterpret_cast<const float4*>(r + j);
    float4 b = *reinterpret_cast<const float4*>(r + DIM + j);
    float4 o;
    float c;
    c = a.x + b.x; o.x = logf(c == 0.f ? EPSV : c);
    c = a.y + b.y; o.y = logf(c == 0.f ? EPSV : c);
    c = a.z + b.z; o.z = logf(c == 0.f ? EPSV : c);
    c = a.w + b.w; o.w = logf(c == 0.f ? EPSV : c);
    *reinterpret_cast<float4*>(out + (size_t)i * 4) = o;
}

// ---------------------------------------------------------------------------
extern "C" void kernel_launch(void* const* d_in, const int* in_sizes, int n_in,
                              void* d_out, int out_size, void* d_ws, size_t ws_size,
                              hipStream_t stream) {
    const float* x   = (const float*)d_in[0];
    const float* emb = (const float*)d_in[1];
    const float* wg  = (const float*)d_in[2];
    const float* w1  = (const float*)d_in[3];
    const float* b1  = (const float*)d_in[4];
    const float* w2  = (const float*)d_in[5];
    const float* b2  = (const float*)d_in[6];
    float* out = (float*)d_out;

    char* ws = (char*)d_ws;
    size_t off = 0;
    auto alloc = [&](size_t n) { size_t p = off; off = (off + n + 255) & ~(size_t)255; return p; };
    int*   counts = (int*)  (ws + alloc(256));
    int*   toks   = (int*)  (ws + alloc((size_t)NEXP * N_TOK * 4));
    float* gates  = (float*)(ws + alloc((size_t)NEXP * N_TOK * 4));
    short* pb1    = (short*)(ws + alloc((size_t)NEXP * DIM * HID * 2));
    short* pb2    = (short*)(ws + alloc((size_t)NEXP * HID * DIM * 2));
    size_t hoff   = alloc((size_t)2 * N_TOK * HID * 2);   // H bf16 rows == slot fp32 rows
    short* Hbuf   = (short*)(ws + hoff);
    float* slotf  = (float*)(ws + hoff);
    size_t xoff   = alloc((size_t)N_TOK * DIM * 2);
    short* xb     = (short*)(ws + xoff);
    bool use_xb = (ws_size >= off);

    hipMemsetAsync(counts, 0, NEXP * sizeof(int), stream);

    const int QF = NEXP * 2 * KT1 * JTL1 * 64;   // 73728 fragments per tensor
    pack_kernel<<<(2 * QF) / 256, 256, 0, stream>>>(w1, w2, pb1, pb2);

    if (use_xb)
        gate_kernel<true><<<N_TOK / 128, 128, 0, stream>>>(x, emb, wg, counts, toks, gates, xb);
    else
        gate_kernel<false><<<N_TOK / 128, 128, 0, stream>>>(x, emb, wg, counts, toks, gates, nullptr);

    if (use_xb)
        h_kernel<true><<<NEXP * 2 * NB, 256, 0, stream>>>(x, xb, pb1, b1, counts, toks, Hbuf);
    else
        h_kernel<false><<<NEXP * 2 * NB, 256, 0, stream>>>(x, nullptr, pb1, b1, counts, toks, Hbuf);

    y_kernel<<<NEXP * 2 * NB, 256, 0, stream>>>(Hbuf, pb2, b2, counts, toks, gates, slotf);

    combine_kernel<<<(N_TOK * DIM / 4) / 256, 256, 0, stream>>>(slotf, out);
}

// Round 4
// 205.484 us; speedup vs baseline: 1.5355x; 1.5355x over previous
//
#include <hip/hip_runtime.h>
#include <hip/hip_bf16.h>

#define N_TOK 32768
#define DIM   192
#define HID   384
#define NEXP  8

#define KT1 6     // DIM/32
#define KT2 12    // HID/32
#define EPSV 2.220446049250313e-16f

typedef __attribute__((ext_vector_type(8))) short short8;
typedef __attribute__((ext_vector_type(4))) short short4v;
typedef __attribute__((ext_vector_type(4))) float f32x4;

static __device__ __forceinline__ short f2bf(float f) {
    union { __hip_bfloat16 h; short s; } u;
    u.h = __float2bfloat16(f);
    return u.s;
}

// ---------------------------------------------------------------------------
// Gating: logits = [x,emb] @ w_gate ; top-2 ; softmax ; scatter to expert
// lists; writes inverse map token->(expert,idx); optionally emits bf16 x.
// ---------------------------------------------------------------------------
template<bool WXB>
__global__ __launch_bounds__(128) void gate_kernel(
    const float* __restrict__ x, const float* __restrict__ emb,
    const float* __restrict__ wg,
    int* __restrict__ counts, int* __restrict__ toks, float* __restrict__ gates,
    int* __restrict__ inv, short* __restrict__ xb)
{
    __shared__ float wgs[2 * DIM * NEXP];   // 12 KB
    __shared__ int cnt[NEXP];
    __shared__ int base[NEXP];
    int tid = threadIdx.x;
    for (int i = tid; i < 2 * DIM * NEXP; i += 128) wgs[i] = wg[i];
    if (tid < NEXP) cnt[tid] = 0;
    __syncthreads();

    int t = blockIdx.x * 128 + tid;
    float acc[NEXP];
#pragma unroll
    for (int e = 0; e < NEXP; ++e) acc[e] = 0.f;

    const float4* xp = reinterpret_cast<const float4*>(x + (size_t)t * DIM);
    const float4* ep = reinterpret_cast<const float4*>(emb + (size_t)t * DIM);
    short* xrow = WXB ? (xb + (size_t)t * DIM) : nullptr;
#pragma unroll 2
    for (int i = 0; i < DIM / 4; ++i) {
        float4 v = xp[i];
        if (WXB) {
            short4v s; s[0] = f2bf(v.x); s[1] = f2bf(v.y); s[2] = f2bf(v.z); s[3] = f2bf(v.w);
            *reinterpret_cast<short4v*>(xrow + i * 4) = s;
        }
        const float* wr = &wgs[(i * 4) * NEXP];
#pragma unroll
        for (int e = 0; e < NEXP; ++e) acc[e] += v.x * wr[e];
#pragma unroll
        for (int e = 0; e < NEXP; ++e) acc[e] += v.y * wr[NEXP + e];
#pragma unroll
        for (int e = 0; e < NEXP; ++e) acc[e] += v.z * wr[2 * NEXP + e];
#pragma unroll
        for (int e = 0; e < NEXP; ++e) acc[e] += v.w * wr[3 * NEXP + e];
    }
#pragma unroll 2
    for (int i = 0; i < DIM / 4; ++i) {
        float4 v = ep[i];
        const float* wr = &wgs[(DIM + i * 4) * NEXP];
#pragma unroll
        for (int e = 0; e < NEXP; ++e) acc[e] += v.x * wr[e];
#pragma unroll
        for (int e = 0; e < NEXP; ++e) acc[e] += v.y * wr[NEXP + e];
#pragma unroll
        for (int e = 0; e < NEXP; ++e) acc[e] += v.z * wr[2 * NEXP + e];
#pragma unroll
        for (int e = 0; e < NEXP; ++e) acc[e] += v.w * wr[3 * NEXP + e];
    }

    int i1 = 0; float l1 = acc[0];
#pragma unroll
    for (int e = 1; e < NEXP; ++e) { if (acc[e] > l1) { l1 = acc[e]; i1 = e; } }
    int i2 = -1; float l2 = -1e30f;
#pragma unroll
    for (int e = 0; e < NEXP; ++e) { if (e != i1 && acc[e] > l2) { l2 = acc[e]; i2 = e; } }
    float g1 = 1.f / (1.f + expf(l2 - l1));
    float g2 = 1.f - g1;

    int p1 = atomicAdd(&cnt[i1], 1);
    int p2 = atomicAdd(&cnt[i2], 1);
    __syncthreads();
    if (tid < NEXP) base[tid] = atomicAdd(&counts[tid], cnt[tid]);
    __syncthreads();
    int o1 = base[i1] + p1;
    int o2 = base[i2] + p2;
    toks[i1 * N_TOK + o1]  = (t << 1);
    gates[i1 * N_TOK + o1] = g1;
    toks[i2 * N_TOK + o2]  = (t << 1) | 1;
    gates[i2 * N_TOK + o2] = g2;
    inv[2 * t]     = (i1 << 17) | o1;
    inv[2 * t + 1] = (i2 << 17) | o2;
}

// ---------------------------------------------------------------------------
// Pack weights -> bf16 MFMA B-fragments, grouped per (e, colgroup):
//   pb1[e][cg(4: 96 cols)][kt(6)][jtl(6)][lane(64)][8]
//   pb2[e][cg(4: 48 cols)][kt(12)][jtl(3)][lane(64)][8]
// One thread = one 16B fragment write (coalesced).
// ---------------------------------------------------------------------------
__global__ __launch_bounds__(256) void pack_kernel(
    const float* __restrict__ w1, const float* __restrict__ w2,
    short* __restrict__ pb1, short* __restrict__ pb2)
{
    const int Q = NEXP * 4 * 36 * 64;   // 73728 fragments per tensor
    int gid = blockIdx.x * 256 + threadIdx.x;
    if (gid < Q) {
        int lane = gid & 63;
        int r = gid >> 6;
        int jtl = r % 6; r /= 6;
        int kt  = r % 6; r /= 6;
        int cg  = r & 3; int e = r >> 2;
        int j  = cg * 96 + jtl * 16 + (lane & 15);
        int k0 = kt * 32 + (lane >> 4) * 8;
        const float* src = w1 + ((size_t)e * DIM + k0) * HID + j;
        short8 s;
#pragma unroll
        for (int t = 0; t < 8; ++t) s[t] = f2bf(src[t * HID]);
        *reinterpret_cast<short8*>(pb1 + (size_t)gid * 8) = s;
    } else if (gid < 2 * Q) {
        int i2 = gid - Q;
        int lane = i2 & 63;
        int r = i2 >> 6;
        int jtl = r % 3;  r /= 3;
        int kt  = r % 12; r /= 12;
        int cg  = r & 3;  int e = r >> 2;
        int j  = cg * 48 + jtl * 16 + (lane & 15);
        int k0 = kt * 32 + (lane >> 4) * 8;
        const float* src = w2 + ((size_t)e * HID + k0) * DIM + j;
        short8 s;
#pragma unroll
        for (int t = 0; t < 8; ++t) s[t] = f2bf(src[t * DIM]);
        *reinterpret_cast<short8*>(pb2 + (size_t)i2 * 8) = s;
    }
}

// ---------------------------------------------------------------------------
// Pass 1: Hp[gbase+idx] = gelu(x[tok(idx)] @ w1[e] + b1)  (expert-permuted rows)
// Weights live in registers (36 frags/wave). No LDS, no barriers.
// block = (e, w); wave = colgroup (96 cols). 512 blocks.
// ---------------------------------------------------------------------------
template<bool USE_XB>
__global__ __launch_bounds__(256, 2) void h_kernel(
    const float* __restrict__ x, const short* __restrict__ xb,
    const short* __restrict__ pb1, const float* __restrict__ b1,
    const int* __restrict__ counts, const int* __restrict__ toks,
    char* __restrict__ Hp)
{
    int b = blockIdx.x;
    int e = b >> 6, w = b & 63;
    int cnt = counts[e];
    int nt = (cnt + 15) >> 4;
    if (w >= nt) return;
    int gbase = 0;
#pragma unroll
    for (int i = 0; i < NEXP; ++i) gbase += (i < e) ? counts[i] : 0;

    int tid = threadIdx.x;
    int cg = tid >> 6, lane = tid & 63;
    int lrow = lane & 15, lgrp = lane >> 4;

    // B-fragments resident in registers: 36 x 16B
    short8 B[KT1][6];
    const short8* pbase = reinterpret_cast<const short8*>(pb1) + (size_t)(e * 4 + cg) * 36 * 64 + lane;
#pragma unroll
    for (int kt = 0; kt < KT1; ++kt)
#pragma unroll
        for (int jtl = 0; jtl < 6; ++jtl)
            B[kt][jtl] = pbase[(kt * 6 + jtl) * 64];

    float bias[6];
#pragma unroll
    for (int j = 0; j < 6; ++j) bias[j] = b1[e * HID + cg * 96 + j * 16 + lrow];

    const int* tl = toks + e * N_TOK;
    short8 a[KT1];
    int rt = w;
    {
        int tok0 = tl[min(rt * 16 + lrow, cnt - 1)];
        if (USE_XB) {
            const char* xr = (const char*)xb + (size_t)(tok0 >> 1) * 384 + lgrp * 16;
#pragma unroll
            for (int kt = 0; kt < KT1; ++kt) a[kt] = *(const short8*)(xr + kt * 64);
        } else {
            const char* xr = (const char*)x + (size_t)(tok0 >> 1) * 768 + lgrp * 32;
#pragma unroll
            for (int kt = 0; kt < KT1; ++kt) {
                float4 a0 = *(const float4*)(xr + kt * 128);
                float4 a1 = *(const float4*)(xr + kt * 128 + 16);
                short8 s;
                s[0] = f2bf(a0.x); s[1] = f2bf(a0.y); s[2] = f2bf(a0.z); s[3] = f2bf(a0.w);
                s[4] = f2bf(a1.x); s[5] = f2bf(a1.y); s[6] = f2bf(a1.z); s[7] = f2bf(a1.w);
                a[kt] = s;
            }
        }
    }

    for (; rt < nt; rt += 64) {
        int rtn = rt + 64;
        bool more = rtn < nt;
        int tokn = 0;
        if (more) tokn = tl[min(rtn * 16 + lrow, cnt - 1)];   // issue early

        f32x4 acc[6];
#pragma unroll
        for (int j = 0; j < 6; ++j) acc[j] = (f32x4){0.f, 0.f, 0.f, 0.f};
#pragma unroll
        for (int kt = 0; kt < KT1; ++kt)
#pragma unroll
            for (int jtl = 0; jtl < 6; ++jtl)
                acc[jtl] = __builtin_amdgcn_mfma_f32_16x16x32_bf16(a[kt], B[kt][jtl], acc[jtl], 0, 0, 0);

        // prefetch next A right after MFMAs; erf-epilogue below hides latency
        if (more) {
            if (USE_XB) {
                const char* xr = (const char*)xb + (size_t)(tokn >> 1) * 384 + lgrp * 16;
#pragma unroll
                for (int kt = 0; kt < KT1; ++kt) a[kt] = *(const short8*)(xr + kt * 64);
            } else {
                const char* xr = (const char*)x + (size_t)(tokn >> 1) * 768 + lgrp * 32;
#pragma unroll
                for (int kt = 0; kt < KT1; ++kt) {
                    float4 a0 = *(const float4*)(xr + kt * 128);
                    float4 a1 = *(const float4*)(xr + kt * 128 + 16);
                    short8 s;
                    s[0] = f2bf(a0.x); s[1] = f2bf(a0.y); s[2] = f2bf(a0.z); s[3] = f2bf(a0.w);
                    s[4] = f2bf(a1.x); s[5] = f2bf(a1.y); s[6] = f2bf(a1.z); s[7] = f2bf(a1.w);
                    a[kt] = s;
                }
            }
        }

#pragma unroll
        for (int rr = 0; rr < 4; ++rr) {
            int r = rt * 16 + lgrp * 4 + rr;
            if (r < cnt) {
                char* hp = Hp + (size_t)(gbase + r) * 768 + cg * 192;
#pragma unroll
                for (int jtl = 0; jtl < 6; ++jtl) {
                    float h = acc[jtl][rr] + bias[jtl];
                    float g = 0.5f * h * (1.f + erff(h * 0.70710678118654752f));
                    *(short*)(hp + (jtl * 16 + lrow) * 2) = f2bf(g);
                }
            }
        }
    }
}

// ---------------------------------------------------------------------------
// Pass 2: slot row g (fp32, SAME buffer as Hp) = gate * exp(Hp[g] @ w2[e] + b2)
// A-reads are contiguous (permuted layout). One s_barrier/iter guards the
// in-place union (all 4 waves' A in regs before any stripe store).
// ---------------------------------------------------------------------------
__global__ __launch_bounds__(256, 2) void y_kernel(
    char* __restrict__ Hb,
    const short* __restrict__ pb2, const float* __restrict__ b2,
    const int* __restrict__ counts, const float* __restrict__ gates)
{
    int b = blockIdx.x;
    int e = b >> 6, w = b & 63;
    int cnt = counts[e];
    int nt = (cnt + 15) >> 4;
    if (w >= nt) return;
    int gbase = 0;
#pragma unroll
    for (int i = 0; i < NEXP; ++i) gbase += (i < e) ? counts[i] : 0;

    int tid = threadIdx.x;
    int cg = tid >> 6, lane = tid & 63;
    int lrow = lane & 15, lgrp = lane >> 4;

    short8 B[KT2][3];
    const short8* pbase = reinterpret_cast<const short8*>(pb2) + (size_t)(e * 4 + cg) * 36 * 64 + lane;
#pragma unroll
    for (int kt = 0; kt < KT2; ++kt)
#pragma unroll
        for (int jtl = 0; jtl < 3; ++jtl)
            B[kt][jtl] = pbase[(kt * 3 + jtl) * 64];

    float bias[3];
#pragma unroll
    for (int j = 0; j < 3; ++j) bias[j] = b2[e * DIM + cg * 48 + j * 16 + lrow];

    const float* gl = gates + e * N_TOK;
    short8 a[KT2];
    int rt = w;
    {
        int idx = min(rt * 16 + lrow, cnt - 1);
        const char* hr = Hb + (size_t)(gbase + idx) * 768 + lgrp * 16;
#pragma unroll
        for (int kt = 0; kt < KT2; ++kt) a[kt] = *(const short8*)(hr + kt * 64);
    }

    for (; rt < nt; rt += 64) {
        int rtn = rt + 64;
        bool more = rtn < nt;
        float gr[4];
#pragma unroll
        for (int rr = 0; rr < 4; ++rr) {
            int r = rt * 16 + lgrp * 4 + rr;
            gr[rr] = (r < cnt) ? gl[r] : 0.f;
        }

        f32x4 acc[3];
#pragma unroll
        for (int j = 0; j < 3; ++j) acc[j] = (f32x4){0.f, 0.f, 0.f, 0.f};
#pragma unroll
        for (int kt = 0; kt < KT2; ++kt)
#pragma unroll
            for (int jtl = 0; jtl < 3; ++jtl)
                acc[jtl] = __builtin_amdgcn_mfma_f32_16x16x32_bf16(a[kt], B[kt][jtl], acc[jtl], 0, 0, 0);

        // all waves have consumed rows(rt) into regs -> safe to overwrite
        asm volatile("s_barrier" ::: "memory");

        if (more) {
            int idx = min(rtn * 16 + lrow, cnt - 1);
            const char* hr = Hb + (size_t)(gbase + idx) * 768 + lgrp * 16;
#pragma unroll
            for (int kt = 0; kt < KT2; ++kt) a[kt] = *(const short8*)(hr + kt * 64);
        }

#pragma unroll
        for (int rr = 0; rr < 4; ++rr) {
            int r = rt * 16 + lgrp * 4 + rr;
            if (r < cnt) {
                char* sp = Hb + (size_t)(gbase + r) * 768 + cg * 192;
#pragma unroll
                for (int jtl = 0; jtl < 3; ++jtl) {
                    float yv = acc[jtl][rr] + bias[jtl];
                    *(float*)(sp + (jtl * 16 + lrow) * 4) = gr[rr] * expf(yv);
                }
            }
        }
    }
}

// ---------------------------------------------------------------------------
// out[t][:] = log(slot[g1(t)][:] + slot[g2(t)][:])
// ---------------------------------------------------------------------------
__global__ __launch_bounds__(256) void combine_kernel(
    const char* __restrict__ Hb, const int* __restrict__ inv,
    const int* __restrict__ counts, float* __restrict__ out)
{
    __shared__ int rb[NEXP];
    int tid = threadIdx.x;
    if (tid < NEXP) {
        int s = 0;
        for (int i = 0; i < tid; ++i) s += counts[i];
        rb[tid] = s;
    }
    __syncthreads();

    int gid = blockIdx.x * 256 + tid;           // over N_TOK*48
    int t = gid / 48, q = gid - t * 48;
    int v1 = inv[2 * t], v2 = inv[2 * t + 1];
    int g1 = rb[v1 >> 17] + (v1 & 0x1FFFF);
    int g2 = rb[v2 >> 17] + (v2 & 0x1FFFF);
    float4 a = *(const float4*)(Hb + (size_t)g1 * 768 + q * 16);
    float4 b = *(const float4*)(Hb + (size_t)g2 * 768 + q * 16);
    float4 o;
    float c;
    c = a.x + b.x; o.x = logf(c == 0.f ? EPSV : c);
    c = a.y + b.y; o.y = logf(c == 0.f ? EPSV : c);
    c = a.z + b.z; o.z = logf(c == 0.f ? EPSV : c);
    c = a.w + b.w; o.w = logf(c == 0.f ? EPSV : c);
    *reinterpret_cast<float4*>(out + (size_t)t * DIM + q * 4) = o;
}

// ---------------------------------------------------------------------------
extern "C" void kernel_launch(void* const* d_in, const int* in_sizes, int n_in,
                              void* d_out, int out_size, void* d_ws, size_t ws_size,
                              hipStream_t stream) {
    const float* x   = (const float*)d_in[0];
    const float* emb = (const float*)d_in[1];
    const float* wg  = (const float*)d_in[2];
    const float* w1  = (const float*)d_in[3];
    const float* b1  = (const float*)d_in[4];
    const float* w2  = (const float*)d_in[5];
    const float* b2  = (const float*)d_in[6];
    float* out = (float*)d_out;

    char* ws = (char*)d_ws;
    size_t off = 0;
    auto alloc = [&](size_t n) { size_t p = off; off = (off + n + 255) & ~(size_t)255; return p; };
    int*   counts = (int*)  (ws + alloc(256));
    int*   toks   = (int*)  (ws + alloc((size_t)NEXP * N_TOK * 4));
    float* gates  = (float*)(ws + alloc((size_t)NEXP * N_TOK * 4));
    int*   inv    = (int*)  (ws + alloc((size_t)2 * N_TOK * 4));
    short* pb1    = (short*)(ws + alloc((size_t)NEXP * DIM * HID * 2));
    short* pb2    = (short*)(ws + alloc((size_t)NEXP * HID * DIM * 2));
    char*  Hp     = (char*) (ws + alloc((size_t)2 * N_TOK * 768));   // H bf16 rows == slot fp32 rows
    size_t xoff   = alloc((size_t)N_TOK * DIM * 2);
    short* xb     = (short*)(ws + xoff);
    bool use_xb = (ws_size >= off);

    hipMemsetAsync(counts, 0, NEXP * sizeof(int), stream);

    const int QF = NEXP * 4 * 36 * 64;
    pack_kernel<<<(2 * QF) / 256, 256, 0, stream>>>(w1, w2, pb1, pb2);

    if (use_xb)
        gate_kernel<true><<<N_TOK / 128, 128, 0, stream>>>(x, emb, wg, counts, toks, gates, inv, xb);
    else
        gate_kernel<false><<<N_TOK / 128, 128, 0, stream>>>(x, emb, wg, counts, toks, gates, inv, nullptr);

    if (use_xb)
        h_kernel<true><<<NEXP * 64, 256, 0, stream>>>(x, xb, pb1, b1, counts, toks, Hp);
    else
        h_kernel<false><<<NEXP * 64, 256, 0, stream>>>(x, nullptr, pb1, b1, counts, toks, Hp);

    y_kernel<<<NEXP * 64, 256, 0, stream>>>(Hp, pb2, b2, counts, gates);

    combine_kernel<<<(N_TOK * 48) / 256, 256, 0, stream>>>(Hp, inv, counts, out);
}